// Round 6
// baseline (1295.481 us; speedup 1.0000x reference)
//
#include <hip/hip_runtime.h>
#include <stdint.h>

#define NN 50000
#define EE 640000
#define DD 128
#define LL 5
#define GG 128
#define D2 256

using bf16x8 = __attribute__((ext_vector_type(8))) short;
using f32x4v = __attribute__((ext_vector_type(4))) float;
using u32x4v = __attribute__((ext_vector_type(4))) unsigned int;

__device__ __forceinline__ unsigned short f2bf(float f){
  union { float f; uint32_t u; } c; c.f = f;
  uint32_t u = c.u;
  uint32_t r = (u + 0x7FFFu + ((u >> 16) & 1u)) >> 16;
  return (unsigned short)r;
}
__device__ __forceinline__ float bf2f(unsigned short u){
  union { uint32_t u; float f; } c; c.u = ((uint32_t)u) << 16; return c.f;
}
__device__ __forceinline__ float bf2f_lo(uint32_t p){
  union { uint32_t u; float f; } c; c.u = p << 16; return c.f;
}
__device__ __forceinline__ float bf2f_hi(uint32_t p){
  union { uint32_t u; float f; } c; c.u = p & 0xFFFF0000u; return c.f;
}

// ---------------- setup kernels ----------------

__global__ __launch_bounds__(256) void zero_kernel(float* p, int n){
  int i = blockIdx.x*256 + threadIdx.x;
  if (i < n) p[i] = 0.f;
}

__global__ __launch_bounds__(256) void count_kernel(const int* __restrict__ ei, int* __restrict__ counts){
  int e = blockIdx.x*256 + threadIdx.x;
  if (e < EE) atomicAdd(&counts[ei[EE + e]], 1);
}

#define SCAN_B 512
__global__ __launch_bounds__(SCAN_B) void scan1_kernel(const int* __restrict__ counts, int* __restrict__ bsums, int n){
  __shared__ int sh[SCAN_B];
  int b = blockIdx.x, t = threadIdx.x;
  int i = b*SCAN_B + t;
  sh[t] = (i < n) ? counts[i] : 0;
  __syncthreads();
  for (int s = SCAN_B/2; s > 0; s >>= 1){
    if (t < s) sh[t] += sh[t+s];
    __syncthreads();
  }
  if (t == 0) bsums[b] = sh[0];
}

__global__ void scan2_kernel(int* bsums, int nb){
  if (threadIdx.x == 0){
    int run = 0;
    for (int i = 0; i < nb; ++i){ int v = bsums[i]; bsums[i] = run; run += v; }
  }
}

__global__ __launch_bounds__(SCAN_B) void scan3_kernel(const int* __restrict__ counts, const int* __restrict__ bsums,
                                                       int* __restrict__ startp, int* __restrict__ cursor, int n){
  __shared__ int sh[SCAN_B];
  int b = blockIdx.x, t = threadIdx.x;
  int i = b*SCAN_B + t;
  int v = (i < n) ? counts[i] : 0;
  sh[t] = v;
  __syncthreads();
  for (int s = 1; s < SCAN_B; s <<= 1){
    int add = (t >= s) ? sh[t-s] : 0;
    __syncthreads();
    sh[t] += add;
    __syncthreads();
  }
  int excl = sh[t] - v + bsums[b];
  if (i < n){ startp[i] = excl; cursor[i] = excl; }
  if (i == n-1) startp[n] = excl + v;
}

__global__ __launch_bounds__(256) void fill_kernel(const int* __restrict__ ei, int* __restrict__ cursor, int* __restrict__ csr){
  int e = blockIdx.x*256 + threadIdx.x;
  if (e < EE){
    int d = ei[EE + e];
    int slot = atomicAdd(&cursor[d], 1);
    csr[slot] = e;
  }
}

// gather edge_attr + src into CSR order (once) -> streaming reads in agg
__global__ __launch_bounds__(256) void egather_kernel(const int* __restrict__ csr, const int* __restrict__ ei,
                                                      const float* __restrict__ ea,
                                                      int* __restrict__ csr_src, float* __restrict__ csr_ea8){
  int s = blockIdx.x*256 + threadIdx.x;
  if (s < EE){
    int e = csr[s];
    csr_src[s] = ei[e];
    float v[8];
    #pragma unroll
    for (int k = 0; k < 7; ++k) v[k] = ea[(size_t)e*7 + k];
    v[7] = 0.f;
    #pragma unroll
    for (int k = 0; k < 8; ++k) csr_ea8[(size_t)s*8 + k] = v[k];
  }
}

__global__ __launch_bounds__(256) void wtrans_kernel(const float* __restrict__ W1, const float* __restrict__ W2,
                                                     unsigned short* __restrict__ W1T, unsigned short* __restrict__ W2T){
  int idx = blockIdx.x*256 + threadIdx.x;
  const int total = LL*DD*D2;
  if (idx < total){
    int l = idx / (DD*D2);
    int rem = idx - l*(DD*D2);
    int k = rem / D2;
    int c = rem - k*D2;
    W1T[(size_t)l*32768 + (size_t)c*128 + k] = f2bf(W1[idx]);
  } else if (idx < 2*total){
    int j = idx - total;
    int l = j / (DD*D2);
    int rem = j - l*(DD*D2);
    int k = rem / DD;
    int c = rem - k*DD;
    W2T[(size_t)l*32768 + (size_t)c*256 + k] = f2bf(W2[j]);
  }
}

// init: hin0 = emb[x] + vn_emb (bf16), pool0 atomics, block0 writes vn
__global__ __launch_bounds__(128) void init_kernel(const int* __restrict__ x, const int* __restrict__ batch,
                                                   const float* __restrict__ emb, const float* __restrict__ vn_emb,
                                                   unsigned short* __restrict__ hin_bf, float* __restrict__ vbuf0,
                                                   float* __restrict__ vn){
  int r0 = blockIdx.x*128;
  int r1 = r0 + 128; if (r1 > NN) r1 = NN;
  int d = threadIdx.x;
  float ve = vn_emb[d];
  if (blockIdx.x == 0){
    for (int g = 0; g < GG; ++g) vn[(size_t)g*DD + d] = ve;
  }
  __shared__ int sb[128];
  __shared__ int sx[128];
  if (r0 + d < r1){ sb[d] = batch[r0 + d]; sx[d] = x[r0 + d]; }
  __syncthreads();
  int curg = sb[0];
  float pacc = 0.f;
  for (int r = r0; r < r1; ++r){
    int g = sb[r - r0];
    if (g != curg){
      atomicAdd(&vbuf0[(size_t)curg*DD + d], pacc);
      pacc = 0.f; curg = g;
    }
    float hv = emb[(size_t)sx[r - r0]*DD + d] + ve;
    hin_bf[(size_t)r*DD + d] = f2bf(hv);
    pacc += hv;
  }
  atomicAdd(&vbuf0[(size_t)curg*DD + d], pacc);
}

// ---------------- per-layer kernels ----------------

// agg3: one wave per node; lane owns features {2*lane, 2*lane+1}.
// z = (1+eps)*hin + sum_e relu(hin[src] + ea@eW + eb) -> bf16 (packed u32 store)
__global__ __launch_bounds__(256) void agg3_kernel(const unsigned short* __restrict__ hin_bf,
                                                   const int* __restrict__ csr_src, const float* __restrict__ csr_ea8,
                                                   const int* __restrict__ startp,
                                                   const float* __restrict__ eW, const float* __restrict__ eb,
                                                   const float* __restrict__ eps, int l,
                                                   unsigned short* __restrict__ zout){
  const int wid  = threadIdx.x >> 6;
  const int lane = threadIdx.x & 63;
  const int node = blockIdx.x*4 + wid;   // NN % 4 == 0
  const int s0 = startp[node], s1 = startp[node+1];
  float2 w[7];
  #pragma unroll
  for (int k = 0; k < 7; ++k) w[k] = *(const float2*)(eW + k*128 + lane*2);
  const float2 bd = *(const float2*)(eb + lane*2);
  float acc0 = 0.f, acc1 = 0.f;
  #pragma unroll 2
  for (int s = s0; s < s1; ++s){
    int src = csr_src[s];                                  // broadcast load
    f32x4v a0 = *(const f32x4v*)(csr_ea8 + (size_t)s*8);   // broadcast
    f32x4v a1 = *(const f32x4v*)(csr_ea8 + (size_t)s*8 + 4);
    uint32_t h2 = *(const uint32_t*)(hin_bf + (size_t)src*128 + lane*2);
    float h0 = bf2f_lo(h2), h1 = bf2f_hi(h2);
    float e0 = bd.x, e1 = bd.y;
    e0 += a0[0]*w[0].x; e1 += a0[0]*w[0].y;
    e0 += a0[1]*w[1].x; e1 += a0[1]*w[1].y;
    e0 += a0[2]*w[2].x; e1 += a0[2]*w[2].y;
    e0 += a0[3]*w[3].x; e1 += a0[3]*w[3].y;
    e0 += a1[0]*w[4].x; e1 += a1[0]*w[4].y;
    e0 += a1[1]*w[5].x; e1 += a1[1]*w[5].y;
    e0 += a1[2]*w[6].x; e1 += a1[2]*w[6].y;
    float m0 = h0 + e0;
    float m1 = h1 + e1;
    acc0 += (m0 > 0.f) ? m0 : 0.f;
    acc1 += (m1 > 0.f) ? m1 : 0.f;
  }
  const float one = 1.f + eps[l];
  uint32_t hs = *(const uint32_t*)(hin_bf + (size_t)node*128 + lane*2);
  float z0 = one*bf2f_lo(hs) + acc0;
  float z1 = one*bf2f_hi(hs) + acc1;
  uint32_t out = (uint32_t)f2bf(z0) | ((uint32_t)f2bf(z1) << 16);
  *(uint32_t*)(zout + (size_t)node*128 + lane*2) = out;
}

// GEMM1: y1h[N,256](bf16) = z_bf16[N,128] @ W1 + b1, column sum/sumsq atomics (fp32)
__global__ __launch_bounds__(256) void gemm1_kernel(const unsigned short* __restrict__ A,
                                                    const unsigned short* __restrict__ BT, // [256][128]
                                                    const float* __restrict__ bias,
                                                    unsigned short* __restrict__ Y,
                                                    float* __restrict__ sums, float* __restrict__ sqs){
  __shared__ __align__(16) unsigned short Al[128*128];
  __shared__ __align__(16) unsigned short Bl[128*128];
  const int t = threadIdx.x;
  const int rb = blockIdx.x, cb = blockIdx.y;
  for (int it = 0; it < 8; ++it){
    int idx = it*256 + t;
    int row = idx >> 4, ch = idx & 15;
    int grow = rb*128 + row;
    u32x4v v = {0,0,0,0};
    if (grow < NN) v = *(const u32x4v*)(A + (size_t)grow*128 + ch*8);
    *(u32x4v*)((char*)Al + row*256 + ((ch*16) ^ ((row&7)<<4))) = v;
  }
  for (int it = 0; it < 8; ++it){
    int idx = it*256 + t;
    int row = idx >> 4, ch = idx & 15;
    u32x4v v = *(const u32x4v*)(BT + (size_t)(cb*128 + row)*128 + ch*8);
    *(u32x4v*)((char*)Bl + row*256 + ((ch*16) ^ ((row&7)<<4))) = v;
  }
  __syncthreads();
  const int lane = t & 63, wave = t >> 6;
  const int wm = wave >> 1, wn = wave & 1;
  const int r0 = lane & 15, kg = lane >> 4;
  f32x4v acc[4][4] = {};
  #pragma unroll
  for (int kk = 0; kk < 4; ++kk){
    const int kb = kk*64 + kg*16;
    bf16x8 a[4], b[4];
    #pragma unroll
    for (int m = 0; m < 4; ++m){
      int row = wm*64 + m*16 + r0;
      a[m] = *(const bf16x8*)((const char*)Al + row*256 + (kb ^ ((r0&7)<<4)));
    }
    #pragma unroll
    for (int n = 0; n < 4; ++n){
      int col = wn*64 + n*16 + r0;
      b[n] = *(const bf16x8*)((const char*)Bl + col*256 + (kb ^ ((r0&7)<<4)));
    }
    #pragma unroll
    for (int m = 0; m < 4; ++m)
      #pragma unroll
      for (int n = 0; n < 4; ++n)
        acc[m][n] = __builtin_amdgcn_mfma_f32_16x16x32_bf16(a[m], b[n], acc[m][n], 0, 0, 0);
  }
  #pragma unroll
  for (int n = 0; n < 4; ++n){
    const int col = cb*128 + wn*64 + n*16 + r0;
    const float bv = bias[col];
    float s = 0.f, q = 0.f;
    #pragma unroll
    for (int m = 0; m < 4; ++m){
      const int rowb = rb*128 + wm*64 + m*16 + kg*4;
      #pragma unroll
      for (int j = 0; j < 4; ++j){
        int grow = rowb + j;
        if (grow < NN){
          float v = acc[m][n][j] + bv;
          Y[(size_t)grow*256 + col] = f2bf(v);
          s += v; q += v*v;
        }
      }
    }
    s += __shfl_xor(s, 16); q += __shfl_xor(q, 16);
    s += __shfl_xor(s, 32); q += __shfl_xor(q, 32);
    if (kg == 0){ atomicAdd(&sums[col], s); atomicAdd(&sqs[col], q); }
  }
}

// GEMM2: y2 = bnrelu(y1h)[N,256] @ W2 + b2; folds BN1 finalize in prologue; column stats.
// FINAL=0: write bf16 to Yh ; FINAL=1: write fp32 to Yf (d_out)
template<int FINAL>
__global__ __launch_bounds__(256) void gemm2_kernel(const unsigned short* __restrict__ Yin,
                                                    const float* __restrict__ sum1, const float* __restrict__ sq1,
                                                    const float* __restrict__ bg, const float* __restrict__ bb,
                                                    const unsigned short* __restrict__ BT, // [128][256]
                                                    const float* __restrict__ bias,
                                                    unsigned short* __restrict__ Yh, float* __restrict__ Yf,
                                                    float* __restrict__ sums, float* __restrict__ sqs){
  __shared__ __align__(16) unsigned short Al[128*128];
  __shared__ __align__(16) unsigned short Bl[128*128];
  __shared__ float s_scl[256], s_shf[256];
  const int t = threadIdx.x;
  const int rb = blockIdx.x;
  {
    const float invn = 1.f/(float)NN;
    float m = sum1[t]*invn;
    float var = sq1[t]*invn - m*m;
    var = var > 0.f ? var : 0.f;
    float sc = bg[t]*rsqrtf(var + 1e-5f);
    s_scl[t] = sc;
    s_shf[t] = bb[t] - m*sc;
  }
  const int lane = t & 63, wave = t >> 6;
  const int wm = wave >> 1, wn = wave & 1;
  const int r0 = lane & 15, kg = lane >> 4;
  f32x4v acc[4][4] = {};
  for (int kt = 0; kt < 2; ++kt){
    __syncthreads();   // kt=0: guards s_scl; kt=1: guards LDS reuse
    for (int it = 0; it < 8; ++it){
      int idx = it*256 + t;
      int row = idx >> 4, ch = idx & 15;
      int grow = rb*128 + row;
      int c0 = kt*128 + ch*8;
      u32x4v pv = {0,0,0,0};
      if (grow < NN){
        u32x4v yv = *(const u32x4v*)(Yin + (size_t)grow*256 + c0);
        unsigned short tb[8];
        #pragma unroll
        for (int jj = 0; jj < 4; ++jj){
          uint32_t pw = yv[jj];
          float a0 = bf2f((unsigned short)(pw & 0xFFFFu));
          float a1 = bf2f((unsigned short)(pw >> 16));
          float v0 = a0*s_scl[c0 + 2*jj]     + s_shf[c0 + 2*jj];
          float v1 = a1*s_scl[c0 + 2*jj + 1] + s_shf[c0 + 2*jj + 1];
          tb[2*jj]     = f2bf(v0 > 0.f ? v0 : 0.f);
          tb[2*jj + 1] = f2bf(v1 > 0.f ? v1 : 0.f);
        }
        pv[0] = (uint32_t)tb[0] | ((uint32_t)tb[1] << 16);
        pv[1] = (uint32_t)tb[2] | ((uint32_t)tb[3] << 16);
        pv[2] = (uint32_t)tb[4] | ((uint32_t)tb[5] << 16);
        pv[3] = (uint32_t)tb[6] | ((uint32_t)tb[7] << 16);
      }
      *(u32x4v*)((char*)Al + row*256 + ((ch*16) ^ ((row&7)<<4))) = pv;
    }
    for (int it = 0; it < 8; ++it){
      int idx = it*256 + t;
      int row = idx >> 4, ch = idx & 15;
      u32x4v v = *(const u32x4v*)(BT + (size_t)row*256 + kt*128 + ch*8);
      *(u32x4v*)((char*)Bl + row*256 + ((ch*16) ^ ((row&7)<<4))) = v;
    }
    __syncthreads();
    #pragma unroll
    for (int kk = 0; kk < 4; ++kk){
      const int kb = kk*64 + kg*16;
      bf16x8 a[4], b[4];
      #pragma unroll
      for (int m = 0; m < 4; ++m){
        int row = wm*64 + m*16 + r0;
        a[m] = *(const bf16x8*)((const char*)Al + row*256 + (kb ^ ((r0&7)<<4)));
      }
      #pragma unroll
      for (int n = 0; n < 4; ++n){
        int col = wn*64 + n*16 + r0;
        b[n] = *(const bf16x8*)((const char*)Bl + col*256 + (kb ^ ((r0&7)<<4)));
      }
      #pragma unroll
      for (int m = 0; m < 4; ++m)
        #pragma unroll
        for (int n = 0; n < 4; ++n)
          acc[m][n] = __builtin_amdgcn_mfma_f32_16x16x32_bf16(a[m], b[n], acc[m][n], 0, 0, 0);
    }
  }
  #pragma unroll
  for (int n = 0; n < 4; ++n){
    const int col = wn*64 + n*16 + r0;
    const float bv = bias[col];
    float s = 0.f, q = 0.f;
    #pragma unroll
    for (int m = 0; m < 4; ++m){
      const int rowb = rb*128 + wm*64 + m*16 + kg*4;
      #pragma unroll
      for (int j = 0; j < 4; ++j){
        int grow = rowb + j;
        if (grow < NN){
          float v = acc[m][n][j] + bv;
          if (FINAL) Yf[(size_t)grow*128 + col] = v;
          else       Yh[(size_t)grow*128 + col] = f2bf(v);
          s += v; q += v*v;
        }
      }
    }
    s += __shfl_xor(s, 16); q += __shfl_xor(q, 16);
    s += __shfl_xor(s, 32); q += __shfl_xor(q, 32);
    if (kg == 0){ atomicAdd(&sums[col], s); atomicAdd(&sqs[col], q); }
  }
}

// happly_fused (l < L-1): read y2(bf16) + stats -> BN+relu -> +vn[batch] -> hin_bf ; pool atomics
__global__ __launch_bounds__(128) void happly_fused_kernel(const unsigned short* __restrict__ y2h,
                                                           const float* __restrict__ sum2, const float* __restrict__ sq2,
                                                           const float* __restrict__ bg, const float* __restrict__ bb,
                                                           const float* __restrict__ vn, const int* __restrict__ batch,
                                                           unsigned short* __restrict__ hin_bf, float* __restrict__ vbuf_next){
  int r0 = blockIdx.x*128;
  int r1 = r0 + 128; if (r1 > NN) r1 = NN;
  int d = threadIdx.x;
  const float invn = 1.f/(float)NN;
  float m = sum2[d]*invn;
  float var = sq2[d]*invn - m*m;
  var = var > 0.f ? var : 0.f;
  float sc = bg[d]*rsqrtf(var + 1e-5f);
  float sh = bb[d] - m*sc;
  __shared__ int sb[128];
  if (r0 + d < r1) sb[d] = batch[r0 + d];
  __syncthreads();
  int curg = sb[0];
  float vnv = vn[(size_t)curg*DD + d];
  float pacc = 0.f;
  for (int r = r0; r < r1; ++r){
    int g = sb[r - r0];
    if (g != curg){
      atomicAdd(&vbuf_next[(size_t)curg*DD + d], pacc);
      pacc = 0.f; curg = g;
      vnv = vn[(size_t)curg*DD + d];
    }
    float y = bf2f(y2h[(size_t)r*DD + d]);
    float v = y*sc + sh;
    v = v > 0.f ? v : 0.f;
    float hv = v + vnv;
    hin_bf[(size_t)r*DD + d] = f2bf(hv);
    pacc += hv;
  }
  atomicAdd(&vbuf_next[(size_t)curg*DD + d], pacc);
}

// final layer: BN in-place on d_out (fp32), no relu
__global__ __launch_bounds__(256) void happly_final_kernel(float* __restrict__ y,
                                                           const float* __restrict__ sum2, const float* __restrict__ sq2,
                                                           const float* __restrict__ bg, const float* __restrict__ bb){
  int idx = blockIdx.x*256 + threadIdx.x;
  if (idx >= NN*32) return;
  int c4 = idx & 31;
  const float invn = 1.f/(float)NN;
  f32x4v yv = *(const f32x4v*)(y + (size_t)idx*4);
  f32x4v o;
  #pragma unroll
  for (int j = 0; j < 4; ++j){
    int c = c4*4 + j;
    float m = sum2[c]*invn;
    float var = sq2[c]*invn - m*m;
    var = var > 0.f ? var : 0.f;
    float sc = bg[c]*rsqrtf(var + 1e-5f);
    o[j] = (yv[j] - m)*sc + bb[c];
  }
  *(f32x4v*)(y + (size_t)idx*4) = o;
}

__global__ __launch_bounds__(256) void vmlp1_kernel(const float* __restrict__ vn, const float* __restrict__ vbufl,
                                                    const float* __restrict__ W, const float* __restrict__ bias,
                                                    float* __restrict__ Yo,
                                                    float* __restrict__ sums, float* __restrict__ sqs){
  __shared__ float vrow[128];
  int r = blockIdx.x, c = threadIdx.x;
  if (c < 128) vrow[c] = vn[r*128 + c] + vbufl[r*128 + c];
  __syncthreads();
  float acc = 0.f;
  #pragma unroll 8
  for (int k = 0; k < 128; ++k) acc += vrow[k]*W[k*256 + c];
  float y = acc + bias[c];
  Yo[r*256 + c] = y;
  atomicAdd(&sums[c], y);
  atomicAdd(&sqs[c], y*y);
}

__global__ __launch_bounds__(128) void vmlp2_kernel(const float* __restrict__ Yin,
                                                    const float* __restrict__ sumv1, const float* __restrict__ sqv1,
                                                    const float* __restrict__ vg, const float* __restrict__ vb,
                                                    const float* __restrict__ W, const float* __restrict__ bias,
                                                    float* __restrict__ Yo,
                                                    float* __restrict__ sums, float* __restrict__ sqs){
  __shared__ float arow[256];
  __shared__ float s_scl[256], s_shf[256];
  int r = blockIdx.x, c = threadIdx.x;
  const float invg = 1.f/(float)GG;
  for (int k = c; k < 256; k += 128){
    float m = sumv1[k]*invg;
    float var = sqv1[k]*invg - m*m;
    var = var > 0.f ? var : 0.f;
    float sc = vg[k]*rsqrtf(var + 1e-5f);
    s_scl[k] = sc;
    s_shf[k] = vb[k] - m*sc;
  }
  __syncthreads();
  for (int k = c; k < 256; k += 128){
    float a = Yin[r*256 + k]*s_scl[k] + s_shf[k];
    arow[k] = a > 0.f ? a : 0.f;
  }
  __syncthreads();
  float acc = 0.f;
  #pragma unroll 8
  for (int k = 0; k < 256; ++k) acc += arow[k]*W[k*128 + c];
  float y = acc + bias[c];
  Yo[r*128 + c] = y;
  atomicAdd(&sums[c], y);
  atomicAdd(&sqs[c], y*y);
}

__global__ __launch_bounds__(256) void va_kernel(const float* __restrict__ yv2,
                                                 const float* __restrict__ sumv2, const float* __restrict__ sqv2,
                                                 const float* __restrict__ vg, const float* __restrict__ vb,
                                                 float* __restrict__ vn){
  int idx = blockIdx.x*256 + threadIdx.x;
  if (idx < GG*128){
    int c = idx & 127;
    const float invg = 1.f/(float)GG;
    float m = sumv2[c]*invg;
    float var = sqv2[c]*invg - m*m;
    var = var > 0.f ? var : 0.f;
    float sc = vg[c]*rsqrtf(var + 1e-5f);
    float v = (yv2[idx] - m)*sc + vb[c];
    vn[idx] = v > 0.f ? v : 0.f;
  }
}

// ---------------- launch ----------------

extern "C" void kernel_launch(void* const* d_in, const int* in_sizes, int n_in,
                              void* d_out, int out_size, void* d_ws, size_t ws_size,
                              hipStream_t stream){
  const int*   x         = (const int*)  d_in[0];
  const int*   ei        = (const int*)  d_in[1];
  const float* edge_attr = (const float*)d_in[2];
  const int*   batch     = (const int*)  d_in[3];
  const float* node_emb  = (const float*)d_in[4];
  const float* vn_emb    = (const float*)d_in[5];
  const float* eps       = (const float*)d_in[6];
  const float* edge_W    = (const float*)d_in[7];
  const float* edge_b    = (const float*)d_in[8];
  const float* W1        = (const float*)d_in[9];
  const float* b1        = (const float*)d_in[10];
  const float* bn1_g     = (const float*)d_in[11];
  const float* bn1_b     = (const float*)d_in[12];
  const float* W2        = (const float*)d_in[13];
  const float* b2        = (const float*)d_in[14];
  const float* bn_g      = (const float*)d_in[15];
  const float* bn_b      = (const float*)d_in[16];
  const float* vn_W1     = (const float*)d_in[17];
  const float* vn_b1     = (const float*)d_in[18];
  const float* vn_bn1_g  = (const float*)d_in[19];
  const float* vn_bn1_b  = (const float*)d_in[20];
  const float* vn_W2     = (const float*)d_in[21];
  const float* vn_b2     = (const float*)d_in[22];
  const float* vn_bn2_g  = (const float*)d_in[23];
  const float* vn_bn2_b  = (const float*)d_in[24];
  float* hout = (float*)d_out;

  char* ws = (char*)d_ws;
  size_t off = 0;
  auto alloc = [&](size_t bytes)->char*{
    char* p = ws + off; off += (bytes + 255) & ~(size_t)255; return p;
  };
  unsigned short* hin_bf = (unsigned short*)alloc((size_t)NN*DD*2);
  unsigned short* zy     = (unsigned short*)alloc((size_t)NN*DD*2);   // zbuf / y2h (disjoint lifetimes)
  unsigned short* y1h    = (unsigned short*)alloc((size_t)NN*D2*2);
  float*          vn     = (float*)         alloc((size_t)GG*DD*4);
  float*          yv1    = (float*)         alloc((size_t)GG*D2*4);
  float*          yv2    = (float*)         alloc((size_t)GG*DD*4);
  unsigned short* W1T    = (unsigned short*)alloc((size_t)LL*D2*DD*2);
  unsigned short* W2T    = (unsigned short*)alloc((size_t)LL*D2*DD*2);
  // zero region: stats_all [LL][8][256] | vbuf_all [5][GG*DD] | counts [NN]
  const int STATS_F = LL*8*256;          // 10240
  const int VBUF_F  = 5*GG*DD;           // 81920
  const int ZTOT    = STATS_F + VBUF_F + NN;
  float* zeroreg = (float*)alloc((size_t)ZTOT*4);
  float* stats_all = zeroreg;
  float* vbuf_all  = zeroreg + STATS_F;
  int*   counts    = (int*)(zeroreg + STATS_F + VBUF_F);
  int*   startp = (int*)  alloc((size_t)(NN+1)*4);
  int*   cursor = (int*)  alloc((size_t)NN*4);
  int*   csr    = (int*)  alloc((size_t)EE*4);
  int*   bsums  = (int*)  alloc(128*4);
  int*   csr_src= (int*)  alloc((size_t)EE*4);
  float* csr_ea8= (float*)alloc((size_t)EE*8*4);

  const int nb_scan = (NN + SCAN_B - 1)/SCAN_B;   // 98
  const int row_blocks = (NN + 127)/128;           // 391
  const int ew_blocks = (NN*32 + 255)/256;         // 6250

  // ---- setup ----
  zero_kernel<<<(ZTOT + 255)/256, 256, 0, stream>>>(zeroreg, ZTOT);
  count_kernel<<<EE/256, 256, 0, stream>>>(ei, counts);
  scan1_kernel<<<nb_scan, SCAN_B, 0, stream>>>(counts, bsums, NN);
  scan2_kernel<<<1, 64, 0, stream>>>(bsums, nb_scan);
  scan3_kernel<<<nb_scan, SCAN_B, 0, stream>>>(counts, bsums, startp, cursor, NN);
  fill_kernel<<<EE/256, 256, 0, stream>>>(ei, cursor, csr);
  egather_kernel<<<EE/256, 256, 0, stream>>>(csr, ei, edge_attr, csr_src, csr_ea8);
  wtrans_kernel<<<(2*LL*DD*D2 + 255)/256, 256, 0, stream>>>(W1, W2, W1T, W2T);
  init_kernel<<<row_blocks, 128, 0, stream>>>(x, batch, node_emb, vn_emb, hin_bf, vbuf_all, vn);

  for (int l = 0; l < LL; ++l){
    float* st    = stats_all + (size_t)l*8*256;
    float* sum1  = st + 0*256, *sq1  = st + 1*256;
    float* sum2  = st + 2*256, *sq2  = st + 3*256;
    float* sumv1 = st + 4*256, *sqv1 = st + 5*256;
    float* sumv2 = st + 6*256, *sqv2 = st + 7*256;

    agg3_kernel<<<NN/4, 256, 0, stream>>>(hin_bf, csr_src, csr_ea8, startp,
                                          edge_W + (size_t)l*7*DD, edge_b + (size_t)l*DD, eps, l, zy);
    gemm1_kernel<<<dim3(row_blocks, 2), 256, 0, stream>>>(zy, W1T + (size_t)l*32768,
                                                          b1 + (size_t)l*D2, y1h, sum1, sq1);
    if (l != LL-1){
      gemm2_kernel<0><<<row_blocks, 256, 0, stream>>>(y1h, sum1, sq1,
                                                      bn1_g + (size_t)l*D2, bn1_b + (size_t)l*D2,
                                                      W2T + (size_t)l*32768, b2 + (size_t)l*DD,
                                                      zy, nullptr, sum2, sq2);
      float* vbufl = vbuf_all + (size_t)l*GG*DD;
      float* vbufn = vbuf_all + (size_t)(l+1)*GG*DD;
      vmlp1_kernel<<<GG, 256, 0, stream>>>(vn, vbufl, vn_W1 + (size_t)l*DD*D2, vn_b1 + (size_t)l*D2,
                                           yv1, sumv1, sqv1);
      vmlp2_kernel<<<GG, 128, 0, stream>>>(yv1, sumv1, sqv1,
                                           vn_bn1_g + (size_t)l*D2, vn_bn1_b + (size_t)l*D2,
                                           vn_W2 + (size_t)l*D2*DD, vn_b2 + (size_t)l*DD,
                                           yv2, sumv2, sqv2);
      va_kernel<<<(GG*DD + 255)/256, 256, 0, stream>>>(yv2, sumv2, sqv2,
                                                       vn_bn2_g + (size_t)l*DD, vn_bn2_b + (size_t)l*DD, vn);
      happly_fused_kernel<<<row_blocks, 128, 0, stream>>>(zy, sum2, sq2,
                                                          bn_g + (size_t)l*DD, bn_b + (size_t)l*DD,
                                                          vn, batch, hin_bf, vbufn);
    } else {
      gemm2_kernel<1><<<row_blocks, 256, 0, stream>>>(y1h, sum1, sq1,
                                                      bn1_g + (size_t)l*D2, bn1_b + (size_t)l*D2,
                                                      W2T + (size_t)l*32768, b2 + (size_t)l*DD,
                                                      nullptr, hout, sum2, sq2);
      happly_final_kernel<<<ew_blocks, 256, 0, stream>>>(hout, sum2, sq2,
                                                         bn_g + (size_t)l*DD, bn_b + (size_t)l*DD);
    }
  }
  (void)in_sizes; (void)n_in; (void)out_size; (void)ws_size;
}

// Round 8
// 1262.595 us; speedup vs baseline: 1.0260x; 1.0260x over previous
//
#include <hip/hip_runtime.h>
#include <stdint.h>

#define NN 50000
#define EE 640000
#define DD 128
#define LL 5
#define GG 128
#define D2 256
#define CSRP_MAX 790016   // EE + 3*NN rounded up

using bf16x8 = __attribute__((ext_vector_type(8))) short;
using f32x4v = __attribute__((ext_vector_type(4))) float;
using u32x4v = __attribute__((ext_vector_type(4))) unsigned int;

__device__ __forceinline__ unsigned short f2bf(float f){
  union { float f; uint32_t u; } c; c.f = f;
  uint32_t u = c.u;
  uint32_t r = (u + 0x7FFFu + ((u >> 16) & 1u)) >> 16;
  return (unsigned short)r;
}
__device__ __forceinline__ float bf2f(unsigned short u){
  union { uint32_t u; float f; } c; c.u = ((uint32_t)u) << 16; return c.f;
}
__device__ __forceinline__ float bf2f_lo(uint32_t p){
  union { uint32_t u; float f; } c; c.u = p << 16; return c.f;
}
__device__ __forceinline__ float bf2f_hi(uint32_t p){
  union { uint32_t u; float f; } c; c.u = p & 0xFFFF0000u; return c.f;
}

// ---------------- setup kernels ----------------

__global__ __launch_bounds__(256) void zero_kernel(float* p, int n){
  int i = blockIdx.x*256 + threadIdx.x;
  if (i < n) p[i] = 0.f;
}

__global__ __launch_bounds__(256) void count_kernel(const int* __restrict__ ei, int* __restrict__ counts){
  int e = blockIdx.x*256 + threadIdx.x;
  if (e < EE) atomicAdd(&counts[ei[EE + e]], 1);
}

#define SCAN_B 512
// padded scan: each node's segment rounded up to multiple of 4
__global__ __launch_bounds__(SCAN_B) void scan1_kernel(const int* __restrict__ counts, int* __restrict__ bsums, int n){
  __shared__ int sh[SCAN_B];
  int b = blockIdx.x, t = threadIdx.x;
  int i = b*SCAN_B + t;
  sh[t] = (i < n) ? ((counts[i] + 3) & ~3) : 0;
  __syncthreads();
  for (int s = SCAN_B/2; s > 0; s >>= 1){
    if (t < s) sh[t] += sh[t+s];
    __syncthreads();
  }
  if (t == 0) bsums[b] = sh[0];
}

__global__ void scan2_kernel(int* bsums, int nb){
  if (threadIdx.x == 0){
    int run = 0;
    for (int i = 0; i < nb; ++i){ int v = bsums[i]; bsums[i] = run; run += v; }
  }
}

__global__ __launch_bounds__(SCAN_B) void scan3_kernel(const int* __restrict__ counts, const int* __restrict__ bsums,
                                                       int* __restrict__ startp, int* __restrict__ cursor, int n){
  __shared__ int sh[SCAN_B];
  int b = blockIdx.x, t = threadIdx.x;
  int i = b*SCAN_B + t;
  int v = (i < n) ? ((counts[i] + 3) & ~3) : 0;
  sh[t] = v;
  __syncthreads();
  for (int s = 1; s < SCAN_B; s <<= 1){
    int add = (t >= s) ? sh[t-s] : 0;
    __syncthreads();
    sh[t] += add;
    __syncthreads();
  }
  int excl = sh[t] - v + bsums[b];
  if (i < n){ startp[i] = excl; cursor[i] = excl; }
  if (i == n-1) startp[n] = excl + v;
}

// pre-init padded CSR: sentinel src = NN (hin pad row = -inf), ea = 0
__global__ __launch_bounds__(256) void csrinit_kernel(int* __restrict__ csr_src, unsigned short* __restrict__ csr_eah){
  int i = blockIdx.x*256 + threadIdx.x;
  if (i < CSRP_MAX){
    csr_src[i] = NN;
    u32x4v z = {0,0,0,0};
    *(u32x4v*)(csr_eah + (size_t)i*8) = z;
  }
}

// fill CSR slots: src index + bf16-packed edge attrs (7 + 1 pad)
__global__ __launch_bounds__(256) void fillcvt_kernel(const int* __restrict__ ei, const float* __restrict__ ea,
                                                      int* __restrict__ cursor,
                                                      int* __restrict__ csr_src, unsigned short* __restrict__ csr_eah){
  int e = blockIdx.x*256 + threadIdx.x;
  if (e < EE){
    int d = ei[EE + e];
    int slot = atomicAdd(&cursor[d], 1);
    csr_src[slot] = ei[e];
    unsigned short t[8];
    #pragma unroll
    for (int k = 0; k < 7; ++k) t[k] = f2bf(ea[(size_t)e*7 + k]);
    t[7] = 0;
    u32x4v pv;
    pv[0] = (uint32_t)t[0] | ((uint32_t)t[1] << 16);
    pv[1] = (uint32_t)t[2] | ((uint32_t)t[3] << 16);
    pv[2] = (uint32_t)t[4] | ((uint32_t)t[5] << 16);
    pv[3] = (uint32_t)t[6] | ((uint32_t)t[7] << 16);
    *(u32x4v*)(csr_eah + (size_t)slot*8) = pv;
  }
}

__global__ __launch_bounds__(256) void wtrans_kernel(const float* __restrict__ W1, const float* __restrict__ W2,
                                                     unsigned short* __restrict__ W1T, unsigned short* __restrict__ W2T){
  int idx = blockIdx.x*256 + threadIdx.x;
  const int total = LL*DD*D2;
  if (idx < total){
    int l = idx / (DD*D2);
    int rem = idx - l*(DD*D2);
    int k = rem / D2;
    int c = rem - k*D2;
    W1T[(size_t)l*32768 + (size_t)c*128 + k] = f2bf(W1[idx]);
  } else if (idx < 2*total){
    int j = idx - total;
    int l = j / (DD*D2);
    int rem = j - l*(DD*D2);
    int k = rem / DD;
    int c = rem - k*DD;
    W2T[(size_t)l*32768 + (size_t)c*256 + k] = f2bf(W2[j]);
  }
}

// init: hin0 = emb[x] + vn_emb (bf16), pool0 atomics, block0 writes vn + hin pad row (-inf)
__global__ __launch_bounds__(128) void init_kernel(const int* __restrict__ x, const int* __restrict__ batch,
                                                   const float* __restrict__ emb, const float* __restrict__ vn_emb,
                                                   unsigned short* __restrict__ hin_bf, float* __restrict__ vbuf0,
                                                   float* __restrict__ vn){
  int r0 = blockIdx.x*128;
  int r1 = r0 + 128; if (r1 > NN) r1 = NN;
  int d = threadIdx.x;
  float ve = vn_emb[d];
  if (blockIdx.x == 0){
    for (int g = 0; g < GG; ++g) vn[(size_t)g*DD + d] = ve;
    hin_bf[(size_t)NN*DD + d] = 0xFF80u;   // bf16 -inf pad row for CSR sentinels
  }
  __shared__ int sb[128];
  __shared__ int sx[128];
  if (r0 + d < r1){ sb[d] = batch[r0 + d]; sx[d] = x[r0 + d]; }
  __syncthreads();
  int curg = sb[0];
  float pacc = 0.f;
  for (int r = r0; r < r1; ++r){
    int g = sb[r - r0];
    if (g != curg){
      atomicAdd(&vbuf0[(size_t)curg*DD + d], pacc);
      pacc = 0.f; curg = g;
    }
    float hv = emb[(size_t)sx[r - r0]*DD + d] + ve;
    hin_bf[(size_t)r*DD + d] = f2bf(hv);
    pacc += hv;
  }
  atomicAdd(&vbuf0[(size_t)curg*DD + d], pacc);
}

// ---------------- per-layer kernels ----------------

// agg4: one wave per node; lane owns features {2*lane, 2*lane+1}; 4-edge batches (CSR padded).
// z = (1+eps)*hin + sum_e relu(hin[src] + ea@eW + eb) -> bf16 packed
__global__ __launch_bounds__(256) void agg4_kernel(const unsigned short* __restrict__ hin_bf,
                                                   const int* __restrict__ csr_src,
                                                   const unsigned short* __restrict__ csr_eah,
                                                   const int* __restrict__ startp,
                                                   const float* __restrict__ eW, const float* __restrict__ eb,
                                                   const float* __restrict__ eps, int l,
                                                   unsigned short* __restrict__ zout){
  const int wid  = threadIdx.x >> 6;
  const int lane = threadIdx.x & 63;
  const int node = blockIdx.x*4 + wid;   // NN % 4 == 0
  const int s0 = startp[node], s1 = startp[node+1];   // multiples of 4
  float2 w[7];
  #pragma unroll
  for (int k = 0; k < 7; ++k) w[k] = *(const float2*)(eW + k*128 + lane*2);
  const float2 bd = *(const float2*)(eb + lane*2);
  float acc0 = 0.f, acc1 = 0.f;
  for (int s = s0; s < s1; s += 4){
    const int4 sv = *(const int4*)(csr_src + s);
    u32x4v p0 = *(const u32x4v*)(csr_eah + (size_t)s*8);
    u32x4v p1 = *(const u32x4v*)(csr_eah + (size_t)s*8 + 8);
    u32x4v p2 = *(const u32x4v*)(csr_eah + (size_t)s*8 + 16);
    u32x4v p3 = *(const u32x4v*)(csr_eah + (size_t)s*8 + 24);
    uint32_t h0 = *(const uint32_t*)(hin_bf + (size_t)sv.x*128 + lane*2);
    uint32_t h1 = *(const uint32_t*)(hin_bf + (size_t)sv.y*128 + lane*2);
    uint32_t h2 = *(const uint32_t*)(hin_bf + (size_t)sv.z*128 + lane*2);
    uint32_t h3 = *(const uint32_t*)(hin_bf + (size_t)sv.w*128 + lane*2);
#define EDGE(P, H) { \
    float a0v = bf2f_lo(P[0]), a1v = bf2f_hi(P[0]); \
    float a2v = bf2f_lo(P[1]), a3v = bf2f_hi(P[1]); \
    float a4v = bf2f_lo(P[2]), a5v = bf2f_hi(P[2]); \
    float a6v = bf2f_lo(P[3]); \
    float e0 = bd.x + a0v*w[0].x + a1v*w[1].x + a2v*w[2].x + a3v*w[3].x + a4v*w[4].x + a5v*w[5].x + a6v*w[6].x; \
    float e1 = bd.y + a0v*w[0].y + a1v*w[1].y + a2v*w[2].y + a3v*w[3].y + a4v*w[4].y + a5v*w[5].y + a6v*w[6].y; \
    float m0 = bf2f_lo(H) + e0, m1 = bf2f_hi(H) + e1; \
    acc0 += (m0 > 0.f) ? m0 : 0.f; \
    acc1 += (m1 > 0.f) ? m1 : 0.f; }
    EDGE(p0, h0)
    EDGE(p1, h1)
    EDGE(p2, h2)
    EDGE(p3, h3)
#undef EDGE
  }
  const float one = 1.f + eps[l];
  uint32_t hs = *(const uint32_t*)(hin_bf + (size_t)node*128 + lane*2);
  float z0 = one*bf2f_lo(hs) + acc0;
  float z1 = one*bf2f_hi(hs) + acc1;
  uint32_t out = (uint32_t)f2bf(z0) | ((uint32_t)f2bf(z1) << 16);
  *(uint32_t*)(zout + (size_t)node*128 + lane*2) = out;
}

// GEMM1: y1h[N,256](bf16) = z_bf16[N,128] @ W1 + b1, column sum/sumsq atomics (fp32)
__global__ __launch_bounds__(256) void gemm1_kernel(const unsigned short* __restrict__ A,
                                                    const unsigned short* __restrict__ BT, // [256][128]
                                                    const float* __restrict__ bias,
                                                    unsigned short* __restrict__ Y,
                                                    float* __restrict__ sums, float* __restrict__ sqs){
  __shared__ __align__(16) unsigned short Al[128*128];
  __shared__ __align__(16) unsigned short Bl[128*128];
  const int t = threadIdx.x;
  const int rb = blockIdx.x, cb = blockIdx.y;
  for (int it = 0; it < 8; ++it){
    int idx = it*256 + t;
    int row = idx >> 4, ch = idx & 15;
    int grow = rb*128 + row;
    u32x4v v = {0,0,0,0};
    if (grow < NN) v = *(const u32x4v*)(A + (size_t)grow*128 + ch*8);
    *(u32x4v*)((char*)Al + row*256 + ((ch*16) ^ ((row&7)<<4))) = v;
  }
  for (int it = 0; it < 8; ++it){
    int idx = it*256 + t;
    int row = idx >> 4, ch = idx & 15;
    u32x4v v = *(const u32x4v*)(BT + (size_t)(cb*128 + row)*128 + ch*8);
    *(u32x4v*)((char*)Bl + row*256 + ((ch*16) ^ ((row&7)<<4))) = v;
  }
  __syncthreads();
  const int lane = t & 63, wave = t >> 6;
  const int wm = wave >> 1, wn = wave & 1;
  const int r0 = lane & 15, kg = lane >> 4;
  f32x4v acc[4][4] = {};
  #pragma unroll
  for (int kk = 0; kk < 4; ++kk){
    const int kb = kk*64 + kg*16;
    bf16x8 a[4], b[4];
    #pragma unroll
    for (int m = 0; m < 4; ++m){
      int row = wm*64 + m*16 + r0;
      a[m] = *(const bf16x8*)((const char*)Al + row*256 + (kb ^ ((r0&7)<<4)));
    }
    #pragma unroll
    for (int n = 0; n < 4; ++n){
      int col = wn*64 + n*16 + r0;
      b[n] = *(const bf16x8*)((const char*)Bl + col*256 + (kb ^ ((r0&7)<<4)));
    }
    #pragma unroll
    for (int m = 0; m < 4; ++m)
      #pragma unroll
      for (int n = 0; n < 4; ++n)
        acc[m][n] = __builtin_amdgcn_mfma_f32_16x16x32_bf16(a[m], b[n], acc[m][n], 0, 0, 0);
  }
  #pragma unroll
  for (int n = 0; n < 4; ++n){
    const int col = cb*128 + wn*64 + n*16 + r0;
    const float bv = bias[col];
    float s = 0.f, q = 0.f;
    #pragma unroll
    for (int m = 0; m < 4; ++m){
      const int rowb = rb*128 + wm*64 + m*16 + kg*4;
      #pragma unroll
      for (int j = 0; j < 4; ++j){
        int grow = rowb + j;
        if (grow < NN){
          float v = acc[m][n][j] + bv;
          Y[(size_t)grow*256 + col] = f2bf(v);
          s += v; q += v*v;
        }
      }
    }
    s += __shfl_xor(s, 16); q += __shfl_xor(q, 16);
    s += __shfl_xor(s, 32); q += __shfl_xor(q, 32);
    if (kg == 0){ atomicAdd(&sums[col], s); atomicAdd(&sqs[col], q); }
  }
}

// GEMM2: y2 = bnrelu(y1h)[N,256] @ W2 + b2; folds BN1 finalize in prologue; column stats.
// FINAL=0: write bf16 to Yh ; FINAL=1: write fp32 to Yf (d_out)
template<int FINAL>
__global__ __launch_bounds__(256) void gemm2_kernel(const unsigned short* __restrict__ Yin,
                                                    const float* __restrict__ sum1, const float* __restrict__ sq1,
                                                    const float* __restrict__ bg, const float* __restrict__ bb,
                                                    const unsigned short* __restrict__ BT, // [128][256]
                                                    const float* __restrict__ bias,
                                                    unsigned short* __restrict__ Yh, float* __restrict__ Yf,
                                                    float* __restrict__ sums, float* __restrict__ sqs){
  __shared__ __align__(16) unsigned short Al[128*128];
  __shared__ __align__(16) unsigned short Bl[128*128];
  __shared__ float s_scl[256], s_shf[256];
  const int t = threadIdx.x;
  const int rb = blockIdx.x;
  {
    const float invn = 1.f/(float)NN;
    float m = sum1[t]*invn;
    float var = sq1[t]*invn - m*m;
    var = var > 0.f ? var : 0.f;
    float sc = bg[t]*rsqrtf(var + 1e-5f);
    s_scl[t] = sc;
    s_shf[t] = bb[t] - m*sc;
  }
  const int lane = t & 63, wave = t >> 6;
  const int wm = wave >> 1, wn = wave & 1;
  const int r0 = lane & 15, kg = lane >> 4;
  f32x4v acc[4][4] = {};
  for (int kt = 0; kt < 2; ++kt){
    __syncthreads();   // kt=0: guards s_scl; kt=1: guards LDS reuse
    for (int it = 0; it < 8; ++it){
      int idx = it*256 + t;
      int row = idx >> 4, ch = idx & 15;
      int grow = rb*128 + row;
      int c0 = kt*128 + ch*8;
      u32x4v pv = {0,0,0,0};
      if (grow < NN){
        u32x4v yv = *(const u32x4v*)(Yin + (size_t)grow*256 + c0);
        unsigned short tb[8];
        #pragma unroll
        for (int jj = 0; jj < 4; ++jj){
          uint32_t pw = yv[jj];
          float a0 = bf2f((unsigned short)(pw & 0xFFFFu));
          float a1 = bf2f((unsigned short)(pw >> 16));
          float v0 = a0*s_scl[c0 + 2*jj]     + s_shf[c0 + 2*jj];
          float v1 = a1*s_scl[c0 + 2*jj + 1] + s_shf[c0 + 2*jj + 1];
          tb[2*jj]     = f2bf(v0 > 0.f ? v0 : 0.f);
          tb[2*jj + 1] = f2bf(v1 > 0.f ? v1 : 0.f);
        }
        pv[0] = (uint32_t)tb[0] | ((uint32_t)tb[1] << 16);
        pv[1] = (uint32_t)tb[2] | ((uint32_t)tb[3] << 16);
        pv[2] = (uint32_t)tb[4] | ((uint32_t)tb[5] << 16);
        pv[3] = (uint32_t)tb[6] | ((uint32_t)tb[7] << 16);
      }
      *(u32x4v*)((char*)Al + row*256 + ((ch*16) ^ ((row&7)<<4))) = pv;
    }
    for (int it = 0; it < 8; ++it){
      int idx = it*256 + t;
      int row = idx >> 4, ch = idx & 15;
      u32x4v v = *(const u32x4v*)(BT + (size_t)row*256 + kt*128 + ch*8);
      *(u32x4v*)((char*)Bl + row*256 + ((ch*16) ^ ((row&7)<<4))) = v;
    }
    __syncthreads();
    #pragma unroll
    for (int kk = 0; kk < 4; ++kk){
      const int kb = kk*64 + kg*16;
      bf16x8 a[4], b[4];
      #pragma unroll
      for (int m = 0; m < 4; ++m){
        int row = wm*64 + m*16 + r0;
        a[m] = *(const bf16x8*)((const char*)Al + row*256 + (kb ^ ((r0&7)<<4)));
      }
      #pragma unroll
      for (int n = 0; n < 4; ++n){
        int col = wn*64 + n*16 + r0;
        b[n] = *(const bf16x8*)((const char*)Bl + col*256 + (kb ^ ((r0&7)<<4)));
      }
      #pragma unroll
      for (int m = 0; m < 4; ++m)
        #pragma unroll
        for (int n = 0; n < 4; ++n)
          acc[m][n] = __builtin_amdgcn_mfma_f32_16x16x32_bf16(a[m], b[n], acc[m][n], 0, 0, 0);
    }
  }
  #pragma unroll
  for (int n = 0; n < 4; ++n){
    const int col = wn*64 + n*16 + r0;
    const float bv = bias[col];
    float s = 0.f, q = 0.f;
    #pragma unroll
    for (int m = 0; m < 4; ++m){
      const int rowb = rb*128 + wm*64 + m*16 + kg*4;
      #pragma unroll
      for (int j = 0; j < 4; ++j){
        int grow = rowb + j;
        if (grow < NN){
          float v = acc[m][n][j] + bv;
          if (FINAL) Yf[(size_t)grow*128 + col] = v;
          else       Yh[(size_t)grow*128 + col] = f2bf(v);
          s += v; q += v*v;
        }
      }
    }
    s += __shfl_xor(s, 16); q += __shfl_xor(q, 16);
    s += __shfl_xor(s, 32); q += __shfl_xor(q, 32);
    if (kg == 0){ atomicAdd(&sums[col], s); atomicAdd(&sqs[col], q); }
  }
}

// happly_fused (l < L-1): read y2(bf16) + stats -> BN+relu -> +vn[batch] -> hin_bf ; pool atomics
__global__ __launch_bounds__(128) void happly_fused_kernel(const unsigned short* __restrict__ y2h,
                                                           const float* __restrict__ sum2, const float* __restrict__ sq2,
                                                           const float* __restrict__ bg, const float* __restrict__ bb,
                                                           const float* __restrict__ vn, const int* __restrict__ batch,
                                                           unsigned short* __restrict__ hin_bf, float* __restrict__ vbuf_next){
  int r0 = blockIdx.x*128;
  int r1 = r0 + 128; if (r1 > NN) r1 = NN;
  int d = threadIdx.x;
  const float invn = 1.f/(float)NN;
  float m = sum2[d]*invn;
  float var = sq2[d]*invn - m*m;
  var = var > 0.f ? var : 0.f;
  float sc = bg[d]*rsqrtf(var + 1e-5f);
  float sh = bb[d] - m*sc;
  __shared__ int sb[128];
  if (r0 + d < r1) sb[d] = batch[r0 + d];
  __syncthreads();
  int curg = sb[0];
  float vnv = vn[(size_t)curg*DD + d];
  float pacc = 0.f;
  for (int r = r0; r < r1; ++r){
    int g = sb[r - r0];
    if (g != curg){
      atomicAdd(&vbuf_next[(size_t)curg*DD + d], pacc);
      pacc = 0.f; curg = g;
      vnv = vn[(size_t)curg*DD + d];
    }
    float y = bf2f(y2h[(size_t)r*DD + d]);
    float v = y*sc + sh;
    v = v > 0.f ? v : 0.f;
    float hv = v + vnv;
    hin_bf[(size_t)r*DD + d] = f2bf(hv);
    pacc += hv;
  }
  atomicAdd(&vbuf_next[(size_t)curg*DD + d], pacc);
}

// final layer: BN in-place on d_out (fp32), no relu
__global__ __launch_bounds__(256) void happly_final_kernel(float* __restrict__ y,
                                                           const float* __restrict__ sum2, const float* __restrict__ sq2,
                                                           const float* __restrict__ bg, const float* __restrict__ bb){
  int idx = blockIdx.x*256 + threadIdx.x;
  if (idx >= NN*32) return;
  int c4 = idx & 31;
  const float invn = 1.f/(float)NN;
  f32x4v yv = *(const f32x4v*)(y + (size_t)idx*4);
  f32x4v o;
  #pragma unroll
  for (int j = 0; j < 4; ++j){
    int c = c4*4 + j;
    float m = sum2[c]*invn;
    float var = sq2[c]*invn - m*m;
    var = var > 0.f ? var : 0.f;
    float sc = bg[c]*rsqrtf(var + 1e-5f);
    o[j] = (yv[j] - m)*sc + bb[c];
  }
  *(f32x4v*)(y + (size_t)idx*4) = o;
}

__global__ __launch_bounds__(256) void vmlp1_kernel(const float* __restrict__ vn, const float* __restrict__ vbufl,
                                                    const float* __restrict__ W, const float* __restrict__ bias,
                                                    float* __restrict__ Yo,
                                                    float* __restrict__ sums, float* __restrict__ sqs){
  __shared__ float vrow[128];
  int r = blockIdx.x, c = threadIdx.x;
  if (c < 128) vrow[c] = vn[r*128 + c] + vbufl[r*128 + c];
  __syncthreads();
  float acc = 0.f;
  #pragma unroll 8
  for (int k = 0; k < 128; ++k) acc += vrow[k]*W[k*256 + c];
  float y = acc + bias[c];
  Yo[r*256 + c] = y;
  atomicAdd(&sums[c], y);
  atomicAdd(&sqs[c], y*y);
}

__global__ __launch_bounds__(128) void vmlp2_kernel(const float* __restrict__ Yin,
                                                    const float* __restrict__ sumv1, const float* __restrict__ sqv1,
                                                    const float* __restrict__ vg, const float* __restrict__ vb,
                                                    const float* __restrict__ W, const float* __restrict__ bias,
                                                    float* __restrict__ Yo,
                                                    float* __restrict__ sums, float* __restrict__ sqs){
  __shared__ float arow[256];
  __shared__ float s_scl[256], s_shf[256];
  int r = blockIdx.x, c = threadIdx.x;
  const float invg = 1.f/(float)GG;
  for (int k = c; k < 256; k += 128){
    float m = sumv1[k]*invg;
    float var = sqv1[k]*invg - m*m;
    var = var > 0.f ? var : 0.f;
    float sc = vg[k]*rsqrtf(var + 1e-5f);
    s_scl[k] = sc;
    s_shf[k] = vb[k] - m*sc;
  }
  __syncthreads();
  for (int k = c; k < 256; k += 128){
    float a = Yin[r*256 + k]*s_scl[k] + s_shf[k];
    arow[k] = a > 0.f ? a : 0.f;
  }
  __syncthreads();
  float acc = 0.f;
  #pragma unroll 8
  for (int k = 0; k < 256; ++k) acc += arow[k]*W[k*128 + c];
  float y = acc + bias[c];
  Yo[r*128 + c] = y;
  atomicAdd(&sums[c], y);
  atomicAdd(&sqs[c], y*y);
}

__global__ __launch_bounds__(256) void va_kernel(const float* __restrict__ yv2,
                                                 const float* __restrict__ sumv2, const float* __restrict__ sqv2,
                                                 const float* __restrict__ vg, const float* __restrict__ vb,
                                                 float* __restrict__ vn){
  int idx = blockIdx.x*256 + threadIdx.x;
  if (idx < GG*128){
    int c = idx & 127;
    const float invg = 1.f/(float)GG;
    float m = sumv2[c]*invg;
    float var = sqv2[c]*invg - m*m;
    var = var > 0.f ? var : 0.f;
    float sc = vg[c]*rsqrtf(var + 1e-5f);
    float v = (yv2[idx] - m)*sc + vb[c];
    vn[idx] = v > 0.f ? v : 0.f;
  }
}

// ---------------- launch ----------------

extern "C" void kernel_launch(void* const* d_in, const int* in_sizes, int n_in,
                              void* d_out, int out_size, void* d_ws, size_t ws_size,
                              hipStream_t stream){
  const int*   x         = (const int*)  d_in[0];
  const int*   ei        = (const int*)  d_in[1];
  const float* edge_attr = (const float*)d_in[2];
  const int*   batch     = (const int*)  d_in[3];
  const float* node_emb  = (const float*)d_in[4];
  const float* vn_emb    = (const float*)d_in[5];
  const float* eps       = (const float*)d_in[6];
  const float* edge_W    = (const float*)d_in[7];
  const float* edge_b    = (const float*)d_in[8];
  const float* W1        = (const float*)d_in[9];
  const float* b1        = (const float*)d_in[10];
  const float* bn1_g     = (const float*)d_in[11];
  const float* bn1_b     = (const float*)d_in[12];
  const float* W2        = (const float*)d_in[13];
  const float* b2        = (const float*)d_in[14];
  const float* bn_g      = (const float*)d_in[15];
  const float* bn_b      = (const float*)d_in[16];
  const float* vn_W1     = (const float*)d_in[17];
  const float* vn_b1     = (const float*)d_in[18];
  const float* vn_bn1_g  = (const float*)d_in[19];
  const float* vn_bn1_b  = (const float*)d_in[20];
  const float* vn_W2     = (const float*)d_in[21];
  const float* vn_b2     = (const float*)d_in[22];
  const float* vn_bn2_g  = (const float*)d_in[23];
  const float* vn_bn2_b  = (const float*)d_in[24];
  float* hout = (float*)d_out;

  char* ws = (char*)d_ws;
  size_t off = 0;
  auto alloc = [&](size_t bytes)->char*{
    char* p = ws + off; off += (bytes + 255) & ~(size_t)255; return p;
  };
  unsigned short* hin_bf = (unsigned short*)alloc((size_t)(NN+1)*DD*2);  // +1 pad row (-inf)
  unsigned short* zy     = (unsigned short*)alloc((size_t)NN*DD*2);   // zbuf / y2h (disjoint lifetimes)
  unsigned short* y1h    = (unsigned short*)alloc((size_t)NN*D2*2);
  float*          vn     = (float*)         alloc((size_t)GG*DD*4);
  float*          yv1    = (float*)         alloc((size_t)GG*D2*4);
  float*          yv2    = (float*)         alloc((size_t)GG*DD*4);
  unsigned short* W1T    = (unsigned short*)alloc((size_t)LL*D2*DD*2);
  unsigned short* W2T    = (unsigned short*)alloc((size_t)LL*D2*DD*2);
  // zero region: stats_all [LL][8][256] | vbuf_all [5][GG*DD] | counts [NN]
  const int STATS_F = LL*8*256;          // 10240
  const int VBUF_F  = 5*GG*DD;           // 81920
  const int ZTOT    = STATS_F + VBUF_F + NN;
  float* zeroreg = (float*)alloc((size_t)ZTOT*4);
  float* stats_all = zeroreg;
  float* vbuf_all  = zeroreg + STATS_F;
  int*   counts    = (int*)(zeroreg + STATS_F + VBUF_F);
  int*   startp = (int*)  alloc((size_t)(NN+1)*4);
  int*   cursor = (int*)  alloc((size_t)NN*4);
  int*   bsums  = (int*)  alloc(128*4);
  int*   csr_src= (int*)  alloc((size_t)CSRP_MAX*4);
  unsigned short* csr_eah = (unsigned short*)alloc((size_t)CSRP_MAX*8*2);

  const int nb_scan = (NN + SCAN_B - 1)/SCAN_B;   // 98
  const int row_blocks = (NN + 127)/128;           // 391
  const int ew_blocks = (NN*32 + 255)/256;         // 6250

  // ---- setup ----
  zero_kernel<<<(ZTOT + 255)/256, 256, 0, stream>>>(zeroreg, ZTOT);
  csrinit_kernel<<<(CSRP_MAX + 255)/256, 256, 0, stream>>>(csr_src, csr_eah);
  count_kernel<<<EE/256, 256, 0, stream>>>(ei, counts);
  scan1_kernel<<<nb_scan, SCAN_B, 0, stream>>>(counts, bsums, NN);
  scan2_kernel<<<1, 64, 0, stream>>>(bsums, nb_scan);
  scan3_kernel<<<nb_scan, SCAN_B, 0, stream>>>(counts, bsums, startp, cursor, NN);
  fillcvt_kernel<<<EE/256, 256, 0, stream>>>(ei, edge_attr, cursor, csr_src, csr_eah);
  wtrans_kernel<<<(2*LL*DD*D2 + 255)/256, 256, 0, stream>>>(W1, W2, W1T, W2T);
  init_kernel<<<row_blocks, 128, 0, stream>>>(x, batch, node_emb, vn_emb, hin_bf, vbuf_all, vn);

  for (int l = 0; l < LL; ++l){
    float* st    = stats_all + (size_t)l*8*256;
    float* sum1  = st + 0*256, *sq1  = st + 1*256;
    float* sum2  = st + 2*256, *sq2  = st + 3*256;
    float* sumv1 = st + 4*256, *sqv1 = st + 5*256;
    float* sumv2 = st + 6*256, *sqv2 = st + 7*256;

    agg4_kernel<<<NN/4, 256, 0, stream>>>(hin_bf, csr_src, csr_eah, startp,
                                          edge_W + (size_t)l*7*DD, edge_b + (size_t)l*DD, eps, l, zy);
    gemm1_kernel<<<dim3(row_blocks, 2), 256, 0, stream>>>(zy, W1T + (size_t)l*32768,
                                                          b1 + (size_t)l*D2, y1h, sum1, sq1);
    if (l != LL-1){
      gemm2_kernel<0><<<row_blocks, 256, 0, stream>>>(y1h, sum1, sq1,
                                                      bn1_g + (size_t)l*D2, bn1_b + (size_t)l*D2,
                                                      W2T + (size_t)l*32768, b2 + (size_t)l*DD,
                                                      zy, nullptr, sum2, sq2);
      float* vbufl = vbuf_all + (size_t)l*GG*DD;
      float* vbufn = vbuf_all + (size_t)(l+1)*GG*DD;
      vmlp1_kernel<<<GG, 256, 0, stream>>>(vn, vbufl, vn_W1 + (size_t)l*DD*D2, vn_b1 + (size_t)l*D2,
                                           yv1, sumv1, sqv1);
      vmlp2_kernel<<<GG, 128, 0, stream>>>(yv1, sumv1, sqv1,
                                           vn_bn1_g + (size_t)l*D2, vn_bn1_b + (size_t)l*D2,
                                           vn_W2 + (size_t)l*D2*DD, vn_b2 + (size_t)l*DD,
                                           yv2, sumv2, sqv2);
      va_kernel<<<(GG*DD + 255)/256, 256, 0, stream>>>(yv2, sumv2, sqv2,
                                                       vn_bn2_g + (size_t)l*DD, vn_bn2_b + (size_t)l*DD, vn);
      happly_fused_kernel<<<row_blocks, 128, 0, stream>>>(zy, sum2, sq2,
                                                          bn_g + (size_t)l*DD, bn_b + (size_t)l*DD,
                                                          vn, batch, hin_bf, vbufn);
    } else {
      gemm2_kernel<1><<<row_blocks, 256, 0, stream>>>(y1h, sum1, sq1,
                                                      bn1_g + (size_t)l*D2, bn1_b + (size_t)l*D2,
                                                      W2T + (size_t)l*32768, b2 + (size_t)l*DD,
                                                      nullptr, hout, sum2, sq2);
      happly_final_kernel<<<ew_blocks, 256, 0, stream>>>(hout, sum2, sq2,
                                                         bn_g + (size_t)l*DD, bn_b + (size_t)l*DD);
    }
  }
  (void)in_sizes; (void)n_in; (void)out_size; (void)ws_size;
}

// Round 10
// 1186.699 us; speedup vs baseline: 1.0917x; 1.0640x over previous
//
#include <hip/hip_runtime.h>
#include <stdint.h>

#define NN 50000
#define EE 640000
#define DD 128
#define LL 5
#define GG 128
#define D2 256
#define CSRP_MAX 790016   // EE + 3*NN rounded up
#define HROWS 32

using bf16x8 = __attribute__((ext_vector_type(8))) short;
using f32x4v = __attribute__((ext_vector_type(4))) float;
using u32x4v = __attribute__((ext_vector_type(4))) unsigned int;

__device__ __forceinline__ unsigned short f2bf(float f){
  union { float f; uint32_t u; } c; c.f = f;
  uint32_t u = c.u;
  uint32_t r = (u + 0x7FFFu + ((u >> 16) & 1u)) >> 16;
  return (unsigned short)r;
}
__device__ __forceinline__ float bf2f(unsigned short u){
  union { uint32_t u; float f; } c; c.u = ((uint32_t)u) << 16; return c.f;
}
__device__ __forceinline__ float bf2f_lo(uint32_t p){
  union { uint32_t u; float f; } c; c.u = p << 16; return c.f;
}
__device__ __forceinline__ float bf2f_hi(uint32_t p){
  union { uint32_t u; float f; } c; c.u = p & 0xFFFF0000u; return c.f;
}

// ---------------- setup kernels ----------------

__global__ __launch_bounds__(256) void zero_kernel(float* p, int n){
  int i = blockIdx.x*256 + threadIdx.x;
  if (i < n) p[i] = 0.f;
}

__global__ __launch_bounds__(256) void count_kernel(const int* __restrict__ ei, int* __restrict__ counts){
  int e = blockIdx.x*256 + threadIdx.x;
  if (e < EE) atomicAdd(&counts[ei[EE + e]], 1);
}

#define SCAN_B 512
// padded scan: each node's segment rounded up to multiple of 4
__global__ __launch_bounds__(SCAN_B) void scan1_kernel(const int* __restrict__ counts, int* __restrict__ bsums, int n){
  __shared__ int sh[SCAN_B];
  int b = blockIdx.x, t = threadIdx.x;
  int i = b*SCAN_B + t;
  sh[t] = (i < n) ? ((counts[i] + 3) & ~3) : 0;
  __syncthreads();
  for (int s = SCAN_B/2; s > 0; s >>= 1){
    if (t < s) sh[t] += sh[t+s];
    __syncthreads();
  }
  if (t == 0) bsums[b] = sh[0];
}

__global__ void scan2_kernel(int* bsums, int nb){
  if (threadIdx.x == 0){
    int run = 0;
    for (int i = 0; i < nb; ++i){ int v = bsums[i]; bsums[i] = run; run += v; }
  }
}

__global__ __launch_bounds__(SCAN_B) void scan3_kernel(const int* __restrict__ counts, const int* __restrict__ bsums,
                                                       int* __restrict__ startp, int* __restrict__ cursor, int n){
  __shared__ int sh[SCAN_B];
  int b = blockIdx.x, t = threadIdx.x;
  int i = b*SCAN_B + t;
  int v = (i < n) ? ((counts[i] + 3) & ~3) : 0;
  sh[t] = v;
  __syncthreads();
  for (int s = 1; s < SCAN_B; s <<= 1){
    int add = (t >= s) ? sh[t-s] : 0;
    __syncthreads();
    sh[t] += add;
    __syncthreads();
  }
  int excl = sh[t] - v + bsums[b];
  if (i < n){ startp[i] = excl; cursor[i] = excl; }
  if (i == n-1) startp[n] = excl + v;
}

// pre-init padded CSR: sentinel src = NN (hin pad row = -inf), ea = 0
__global__ __launch_bounds__(256) void csrinit_kernel(int* __restrict__ csr_src, unsigned short* __restrict__ csr_eah){
  int i = blockIdx.x*256 + threadIdx.x;
  if (i < CSRP_MAX){
    csr_src[i] = NN;
    u32x4v z = {0,0,0,0};
    *(u32x4v*)(csr_eah + (size_t)i*8) = z;
  }
}

// fill CSR slots: src index + bf16-packed edge attrs (7 + 1 pad)
__global__ __launch_bounds__(256) void fillcvt_kernel(const int* __restrict__ ei, const float* __restrict__ ea,
                                                      int* __restrict__ cursor,
                                                      int* __restrict__ csr_src, unsigned short* __restrict__ csr_eah){
  int e = blockIdx.x*256 + threadIdx.x;
  if (e < EE){
    int d = ei[EE + e];
    int slot = atomicAdd(&cursor[d], 1);
    csr_src[slot] = ei[e];
    unsigned short t[8];
    #pragma unroll
    for (int k = 0; k < 7; ++k) t[k] = f2bf(ea[(size_t)e*7 + k]);
    t[7] = 0;
    u32x4v pv;
    pv[0] = (uint32_t)t[0] | ((uint32_t)t[1] << 16);
    pv[1] = (uint32_t)t[2] | ((uint32_t)t[3] << 16);
    pv[2] = (uint32_t)t[4] | ((uint32_t)t[5] << 16);
    pv[3] = (uint32_t)t[6] | ((uint32_t)t[7] << 16);
    *(u32x4v*)(csr_eah + (size_t)slot*8) = pv;
  }
}

__global__ __launch_bounds__(256) void wtrans_kernel(const float* __restrict__ W1, const float* __restrict__ W2,
                                                     unsigned short* __restrict__ W1T, unsigned short* __restrict__ W2T){
  int idx = blockIdx.x*256 + threadIdx.x;
  const int total = LL*DD*D2;
  if (idx < total){
    int l = idx / (DD*D2);
    int rem = idx - l*(DD*D2);
    int k = rem / D2;
    int c = rem - k*D2;
    W1T[(size_t)l*32768 + (size_t)c*128 + k] = f2bf(W1[idx]);
  } else if (idx < 2*total){
    int j = idx - total;
    int l = j / (DD*D2);
    int rem = j - l*(DD*D2);
    int k = rem / DD;
    int c = rem - k*DD;
    W2T[(size_t)l*32768 + (size_t)c*256 + k] = f2bf(W2[j]);
  }
}

// init: hin0 = emb[x] + vn_emb (bf16), pool0 atomics, block0 writes vn + hin pad row (-inf)
__global__ __launch_bounds__(128) void init_kernel(const int* __restrict__ x, const int* __restrict__ batch,
                                                   const float* __restrict__ emb, const float* __restrict__ vn_emb,
                                                   unsigned short* __restrict__ hin_bf, float* __restrict__ vbuf0,
                                                   float* __restrict__ vn){
  int r0 = blockIdx.x*128;
  int r1 = r0 + 128; if (r1 > NN) r1 = NN;
  int d = threadIdx.x;
  float ve = vn_emb[d];
  if (blockIdx.x == 0){
    for (int g = 0; g < GG; ++g) vn[(size_t)g*DD + d] = ve;
    hin_bf[(size_t)NN*DD + d] = 0xFF80u;   // bf16 -inf pad row for CSR sentinels
  }
  __shared__ int sb[128];
  __shared__ int sx[128];
  if (r0 + d < r1){ sb[d] = batch[r0 + d]; sx[d] = x[r0 + d]; }
  __syncthreads();
  int curg = sb[0];
  float pacc = 0.f;
  for (int r = r0; r < r1; ++r){
    int g = sb[r - r0];
    if (g != curg){
      atomicAdd(&vbuf0[(size_t)curg*DD + d], pacc);
      pacc = 0.f; curg = g;
    }
    float hv = emb[(size_t)sx[r - r0]*DD + d] + ve;
    hin_bf[(size_t)r*DD + d] = f2bf(hv);
    pacc += hv;
  }
  atomicAdd(&vbuf0[(size_t)curg*DD + d], pacc);
}

// ---------------- per-layer kernels ----------------

// agg4: one wave per node; lane owns features {2*lane, 2*lane+1}; 4-edge batches (CSR padded).
__global__ __launch_bounds__(256) void agg4_kernel(const unsigned short* __restrict__ hin_bf,
                                                   const int* __restrict__ csr_src,
                                                   const unsigned short* __restrict__ csr_eah,
                                                   const int* __restrict__ startp,
                                                   const float* __restrict__ eW, const float* __restrict__ eb,
                                                   const float* __restrict__ eps, int l,
                                                   unsigned short* __restrict__ zout){
  const int wid  = threadIdx.x >> 6;
  const int lane = threadIdx.x & 63;
  const int node = blockIdx.x*4 + wid;   // NN % 4 == 0
  const int s0 = startp[node], s1 = startp[node+1];   // multiples of 4
  float2 w[7];
  #pragma unroll
  for (int k = 0; k < 7; ++k) w[k] = *(const float2*)(eW + k*128 + lane*2);
  const float2 bd = *(const float2*)(eb + lane*2);
  float acc0 = 0.f, acc1 = 0.f;
  for (int s = s0; s < s1; s += 4){
    const int4 sv = *(const int4*)(csr_src + s);
    u32x4v p0 = *(const u32x4v*)(csr_eah + (size_t)s*8);
    u32x4v p1 = *(const u32x4v*)(csr_eah + (size_t)s*8 + 8);
    u32x4v p2 = *(const u32x4v*)(csr_eah + (size_t)s*8 + 16);
    u32x4v p3 = *(const u32x4v*)(csr_eah + (size_t)s*8 + 24);
    uint32_t h0 = *(const uint32_t*)(hin_bf + (size_t)sv.x*128 + lane*2);
    uint32_t h1 = *(const uint32_t*)(hin_bf + (size_t)sv.y*128 + lane*2);
    uint32_t h2 = *(const uint32_t*)(hin_bf + (size_t)sv.z*128 + lane*2);
    uint32_t h3 = *(const uint32_t*)(hin_bf + (size_t)sv.w*128 + lane*2);
#define EDGE(P, H) { \
    float a0v = bf2f_lo(P[0]), a1v = bf2f_hi(P[0]); \
    float a2v = bf2f_lo(P[1]), a3v = bf2f_hi(P[1]); \
    float a4v = bf2f_lo(P[2]), a5v = bf2f_hi(P[2]); \
    float a6v = bf2f_lo(P[3]); \
    float e0 = bd.x + a0v*w[0].x + a1v*w[1].x + a2v*w[2].x + a3v*w[3].x + a4v*w[4].x + a5v*w[5].x + a6v*w[6].x; \
    float e1 = bd.y + a0v*w[0].y + a1v*w[1].y + a2v*w[2].y + a3v*w[3].y + a4v*w[4].y + a5v*w[5].y + a6v*w[6].y; \
    float m0 = bf2f_lo(H) + e0, m1 = bf2f_hi(H) + e1; \
    acc0 += (m0 > 0.f) ? m0 : 0.f; \
    acc1 += (m1 > 0.f) ? m1 : 0.f; }
    EDGE(p0, h0)
    EDGE(p1, h1)
    EDGE(p2, h2)
    EDGE(p3, h3)
#undef EDGE
  }
  const float one = 1.f + eps[l];
  uint32_t hs = *(const uint32_t*)(hin_bf + (size_t)node*128 + lane*2);
  float z0 = one*bf2f_lo(hs) + acc0;
  float z1 = one*bf2f_hi(hs) + acc1;
  uint32_t out = (uint32_t)f2bf(z0) | ((uint32_t)f2bf(z1) << 16);
  *(uint32_t*)(zout + (size_t)node*128 + lane*2) = out;
}

// GEMM1 (LDS-free): y1h[N,256](bf16) = z_bf16[N,128] @ W1 + b1, column stats atomics.
// A and B fragments read directly from global (L2-resident); no barriers.
__global__ __launch_bounds__(256) void gemm1_kernel(const unsigned short* __restrict__ A,
                                                    const unsigned short* __restrict__ BT, // [256 cols][128 k]
                                                    const float* __restrict__ bias,
                                                    unsigned short* __restrict__ Y,
                                                    float* __restrict__ sums, float* __restrict__ sqs){
  const int t = threadIdx.x;
  const int rb = blockIdx.x, cb = blockIdx.y;
  const int lane = t & 63, wave = t >> 6;
  const int wm = wave >> 1, wn = wave & 1;
  const int r0 = lane & 15, kg = lane >> 4;
  const char* Ab = (const char*)A;
  const char* Bb = (const char*)BT;
  f32x4v acc[4][4] = {};
  #pragma unroll
  for (int kk = 0; kk < 4; ++kk){
    const int kb = kk*64 + kg*16;     // byte offset within 256B row
    bf16x8 a[4], b[4];
    #pragma unroll
    for (int m = 0; m < 4; ++m){
      int row = rb*128 + wm*64 + m*16 + r0;   // OOB rows read scratch garbage; stores guarded
      a[m] = *(const bf16x8*)(Ab + (size_t)row*256 + kb);
    }
    #pragma unroll
    for (int n = 0; n < 4; ++n){
      int colg = cb*128 + wn*64 + n*16 + r0;
      b[n] = *(const bf16x8*)(Bb + (size_t)colg*256 + kb);
    }
    #pragma unroll
    for (int m = 0; m < 4; ++m)
      #pragma unroll
      for (int n = 0; n < 4; ++n)
        acc[m][n] = __builtin_amdgcn_mfma_f32_16x16x32_bf16(a[m], b[n], acc[m][n], 0, 0, 0);
  }
  #pragma unroll
  for (int n = 0; n < 4; ++n){
    const int col = cb*128 + wn*64 + n*16 + r0;
    const float bv = bias[col];
    float s = 0.f, q = 0.f;
    #pragma unroll
    for (int m = 0; m < 4; ++m){
      const int rowb = rb*128 + wm*64 + m*16 + kg*4;
      #pragma unroll
      for (int j = 0; j < 4; ++j){
        int grow = rowb + j;
        if (grow < NN){
          float v = acc[m][n][j] + bv;
          Y[(size_t)grow*256 + col] = f2bf(v);
          s += v; q += v*v;
        }
      }
    }
    s += __shfl_xor(s, 16); q += __shfl_xor(q, 16);
    s += __shfl_xor(s, 32); q += __shfl_xor(q, 32);
    if (kg == 0){ atomicAdd(&sums[col], s); atomicAdd(&sqs[col], q); }
  }
}

// GEMM2: y2 = bnrelu(y1h)[N,256] @ W2 + b2; BN1 finalize in prologue; A staged in LDS,
// B read direct from global. FINAL=0: bf16 to Yh ; FINAL=1: fp32 to Yf (d_out)
template<int FINAL>
__global__ __launch_bounds__(256) void gemm2_kernel(const unsigned short* __restrict__ Yin,
                                                    const float* __restrict__ sum1, const float* __restrict__ sq1,
                                                    const float* __restrict__ bg, const float* __restrict__ bb,
                                                    const unsigned short* __restrict__ BT, // [128 cols][256 k]
                                                    const float* __restrict__ bias,
                                                    unsigned short* __restrict__ Yh, float* __restrict__ Yf,
                                                    float* __restrict__ sums, float* __restrict__ sqs){
  __shared__ __align__(16) unsigned short Al[128*128];
  __shared__ float s_scl[256], s_shf[256];
  const int t = threadIdx.x;
  const int rb = blockIdx.x;
  {
    const float invn = 1.f/(float)NN;
    float m = sum1[t]*invn;
    float var = sq1[t]*invn - m*m;
    var = var > 0.f ? var : 0.f;
    float sc = bg[t]*rsqrtf(var + 1e-5f);
    s_scl[t] = sc;
    s_shf[t] = bb[t] - m*sc;
  }
  const int lane = t & 63, wave = t >> 6;
  const int wm = wave >> 1, wn = wave & 1;
  const int r0 = lane & 15, kg = lane >> 4;
  const char* Bb = (const char*)BT;
  f32x4v acc[4][4] = {};
  for (int kt = 0; kt < 2; ++kt){
    __syncthreads();   // kt=0: guards s_scl; kt=1: guards LDS reuse
    for (int it = 0; it < 8; ++it){
      int idx = it*256 + t;
      int row = idx >> 4, ch = idx & 15;
      int grow = rb*128 + row;
      int c0 = kt*128 + ch*8;
      u32x4v pv = {0,0,0,0};
      if (grow < NN){
        u32x4v yv = *(const u32x4v*)(Yin + (size_t)grow*256 + c0);
        unsigned short tb[8];
        #pragma unroll
        for (int jj = 0; jj < 4; ++jj){
          uint32_t pw = yv[jj];
          float a0 = bf2f((unsigned short)(pw & 0xFFFFu));
          float a1 = bf2f((unsigned short)(pw >> 16));
          float v0 = a0*s_scl[c0 + 2*jj]     + s_shf[c0 + 2*jj];
          float v1 = a1*s_scl[c0 + 2*jj + 1] + s_shf[c0 + 2*jj + 1];
          tb[2*jj]     = f2bf(v0 > 0.f ? v0 : 0.f);
          tb[2*jj + 1] = f2bf(v1 > 0.f ? v1 : 0.f);
        }
        pv[0] = (uint32_t)tb[0] | ((uint32_t)tb[1] << 16);
        pv[1] = (uint32_t)tb[2] | ((uint32_t)tb[3] << 16);
        pv[2] = (uint32_t)tb[4] | ((uint32_t)tb[5] << 16);
        pv[3] = (uint32_t)tb[6] | ((uint32_t)tb[7] << 16);
      }
      *(u32x4v*)((char*)Al + row*256 + ((ch*16) ^ ((row&7)<<4))) = pv;
    }
    __syncthreads();
    #pragma unroll
    for (int kk = 0; kk < 4; ++kk){
      const int kb = kk*64 + kg*16;
      bf16x8 a[4], b[4];
      #pragma unroll
      for (int m = 0; m < 4; ++m){
        int row = wm*64 + m*16 + r0;
        a[m] = *(const bf16x8*)((const char*)Al + row*256 + (kb ^ ((r0&7)<<4)));
      }
      #pragma unroll
      for (int n = 0; n < 4; ++n){
        int colg = wn*64 + n*16 + r0;
        b[n] = *(const bf16x8*)(Bb + (size_t)colg*512 + kt*256 + kb);
      }
      #pragma unroll
      for (int m = 0; m < 4; ++m)
        #pragma unroll
        for (int n = 0; n < 4; ++n)
          acc[m][n] = __builtin_amdgcn_mfma_f32_16x16x32_bf16(a[m], b[n], acc[m][n], 0, 0, 0);
    }
  }
  #pragma unroll
  for (int n = 0; n < 4; ++n){
    const int col = wn*64 + n*16 + r0;
    const float bv = bias[col];
    float s = 0.f, q = 0.f;
    #pragma unroll
    for (int m = 0; m < 4; ++m){
      const int rowb = rb*128 + wm*64 + m*16 + kg*4;
      #pragma unroll
      for (int j = 0; j < 4; ++j){
        int grow = rowb + j;
        if (grow < NN){
          float v = acc[m][n][j] + bv;
          if (FINAL) Yf[(size_t)grow*128 + col] = v;
          else       Yh[(size_t)grow*128 + col] = f2bf(v);
          s += v; q += v*v;
        }
      }
    }
    s += __shfl_xor(s, 16); q += __shfl_xor(q, 16);
    s += __shfl_xor(s, 32); q += __shfl_xor(q, 32);
    if (kg == 0){ atomicAdd(&sums[col], s); atomicAdd(&sqs[col], q); }
  }
}

// happly_fused (l < L-1): read y2(bf16) + stats -> BN+relu -> +vn[batch] -> hin_bf ; pool atomics
// HROWS=32 rows per block for 4x parallelism vs 128
__global__ __launch_bounds__(128) void happly_fused_kernel(const unsigned short* __restrict__ y2h,
                                                           const float* __restrict__ sum2, const float* __restrict__ sq2,
                                                           const float* __restrict__ bg, const float* __restrict__ bb,
                                                           const float* __restrict__ vn, const int* __restrict__ batch,
                                                           unsigned short* __restrict__ hin_bf, float* __restrict__ vbuf_next){
  int r0 = blockIdx.x*HROWS;
  int r1 = r0 + HROWS; if (r1 > NN) r1 = NN;
  int d = threadIdx.x;
  const float invn = 1.f/(float)NN;
  float m = sum2[d]*invn;
  float var = sq2[d]*invn - m*m;
  var = var > 0.f ? var : 0.f;
  float sc = bg[d]*rsqrtf(var + 1e-5f);
  float sh = bb[d] - m*sc;
  __shared__ int sb[HROWS];
  if (d < HROWS && r0 + d < r1) sb[d] = batch[r0 + d];
  __syncthreads();
  int curg = sb[0];
  float vnv = vn[(size_t)curg*DD + d];
  float pacc = 0.f;
  for (int r = r0; r < r1; ++r){
    int g = sb[r - r0];
    if (g != curg){
      atomicAdd(&vbuf_next[(size_t)curg*DD + d], pacc);
      pacc = 0.f; curg = g;
      vnv = vn[(size_t)curg*DD + d];
    }
    float y = bf2f(y2h[(size_t)r*DD + d]);
    float v = y*sc + sh;
    v = v > 0.f ? v : 0.f;
    float hv = v + vnv;
    hin_bf[(size_t)r*DD + d] = f2bf(hv);
    pacc += hv;
  }
  atomicAdd(&vbuf_next[(size_t)curg*DD + d], pacc);
}

// final layer: BN in-place on d_out (fp32), no relu
__global__ __launch_bounds__(256) void happly_final_kernel(float* __restrict__ y,
                                                           const float* __restrict__ sum2, const float* __restrict__ sq2,
                                                           const float* __restrict__ bg, const float* __restrict__ bb){
  int idx = blockIdx.x*256 + threadIdx.x;
  if (idx >= NN*32) return;
  int c4 = idx & 31;
  const float invn = 1.f/(float)NN;
  f32x4v yv = *(const f32x4v*)(y + (size_t)idx*4);
  f32x4v o;
  #pragma unroll
  for (int j = 0; j < 4; ++j){
    int c = c4*4 + j;
    float m = sum2[c]*invn;
    float var = sq2[c]*invn - m*m;
    var = var > 0.f ? var : 0.f;
    float sc = bg[c]*rsqrtf(var + 1e-5f);
    o[j] = (yv[j] - m)*sc + bb[c];
  }
  *(f32x4v*)(y + (size_t)idx*4) = o;
}

__global__ __launch_bounds__(256) void vmlp1_kernel(const float* __restrict__ vn, const float* __restrict__ vbufl,
                                                    const float* __restrict__ W, const float* __restrict__ bias,
                                                    float* __restrict__ Yo,
                                                    float* __restrict__ sums, float* __restrict__ sqs){
  __shared__ float vrow[128];
  int r = blockIdx.x, c = threadIdx.x;
  if (c < 128) vrow[c] = vn[r*128 + c] + vbufl[r*128 + c];
  __syncthreads();
  float acc = 0.f;
  #pragma unroll 8
  for (int k = 0; k < 128; ++k) acc += vrow[k]*W[k*256 + c];
  float y = acc + bias[c];
  Yo[r*256 + c] = y;
  atomicAdd(&sums[c], y);
  atomicAdd(&sqs[c], y*y);
}

__global__ __launch_bounds__(128) void vmlp2_kernel(const float* __restrict__ Yin,
                                                    const float* __restrict__ sumv1, const float* __restrict__ sqv1,
                                                    const float* __restrict__ vg, const float* __restrict__ vb,
                                                    const float* __restrict__ W, const float* __restrict__ bias,
                                                    float* __restrict__ Yo,
                                                    float* __restrict__ sums, float* __restrict__ sqs){
  __shared__ float arow[256];
  __shared__ float s_scl[256], s_shf[256];
  int r = blockIdx.x, c = threadIdx.x;
  const float invg = 1.f/(float)GG;
  for (int k = c; k < 256; k += 128){
    float m = sumv1[k]*invg;
    float var = sqv1[k]*invg - m*m;
    var = var > 0.f ? var : 0.f;
    float sc = vg[k]*rsqrtf(var + 1e-5f);
    s_scl[k] = sc;
    s_shf[k] = vb[k] - m*sc;
  }
  __syncthreads();
  for (int k = c; k < 256; k += 128){
    float a = Yin[r*256 + k]*s_scl[k] + s_shf[k];
    arow[k] = a > 0.f ? a : 0.f;
  }
  __syncthreads();
  float acc = 0.f;
  #pragma unroll 8
  for (int k = 0; k < 256; ++k) acc += arow[k]*W[k*128 + c];
  float y = acc + bias[c];
  Yo[r*128 + c] = y;
  atomicAdd(&sums[c], y);
  atomicAdd(&sqs[c], y*y);
}

__global__ __launch_bounds__(256) void va_kernel(const float* __restrict__ yv2,
                                                 const float* __restrict__ sumv2, const float* __restrict__ sqv2,
                                                 const float* __restrict__ vg, const float* __restrict__ vb,
                                                 float* __restrict__ vn){
  int idx = blockIdx.x*256 + threadIdx.x;
  if (idx < GG*128){
    int c = idx & 127;
    const float invg = 1.f/(float)GG;
    float m = sumv2[c]*invg;
    float var = sqv2[c]*invg - m*m;
    var = var > 0.f ? var : 0.f;
    float sc = vg[c]*rsqrtf(var + 1e-5f);
    float v = (yv2[idx] - m)*sc + vb[c];
    vn[idx] = v > 0.f ? v : 0.f;
  }
}

// ---------------- launch ----------------

extern "C" void kernel_launch(void* const* d_in, const int* in_sizes, int n_in,
                              void* d_out, int out_size, void* d_ws, size_t ws_size,
                              hipStream_t stream){
  const int*   x         = (const int*)  d_in[0];
  const int*   ei        = (const int*)  d_in[1];
  const float* edge_attr = (const float*)d_in[2];
  const int*   batch     = (const int*)  d_in[3];
  const float* node_emb  = (const float*)d_in[4];
  const float* vn_emb    = (const float*)d_in[5];
  const float* eps       = (const float*)d_in[6];
  const float* edge_W    = (const float*)d_in[7];
  const float* edge_b    = (const float*)d_in[8];
  const float* W1        = (const float*)d_in[9];
  const float* b1        = (const float*)d_in[10];
  const float* bn1_g     = (const float*)d_in[11];
  const float* bn1_b     = (const float*)d_in[12];
  const float* W2        = (const float*)d_in[13];
  const float* b2        = (const float*)d_in[14];
  const float* bn_g      = (const float*)d_in[15];
  const float* bn_b      = (const float*)d_in[16];
  const float* vn_W1     = (const float*)d_in[17];
  const float* vn_b1     = (const float*)d_in[18];
  const float* vn_bn1_g  = (const float*)d_in[19];
  const float* vn_bn1_b  = (const float*)d_in[20];
  const float* vn_W2     = (const float*)d_in[21];
  const float* vn_b2     = (const float*)d_in[22];
  const float* vn_bn2_g  = (const float*)d_in[23];
  const float* vn_bn2_b  = (const float*)d_in[24];
  float* hout = (float*)d_out;

  char* ws = (char*)d_ws;
  size_t off = 0;
  auto alloc = [&](size_t bytes)->char*{
    char* p = ws + off; off += (bytes + 255) & ~(size_t)255; return p;
  };
  unsigned short* hin_bf = (unsigned short*)alloc((size_t)(NN+1)*DD*2);  // +1 pad row (-inf)
  unsigned short* zy     = (unsigned short*)alloc((size_t)(NN+64)*DD*2); // zbuf / y2h (+pad for OOB reads)
  unsigned short* y1h    = (unsigned short*)alloc((size_t)(NN+64)*D2*2); // +pad for OOB reads
  float*          vn     = (float*)         alloc((size_t)GG*DD*4);
  float*          yv1    = (float*)         alloc((size_t)GG*D2*4);
  float*          yv2    = (float*)         alloc((size_t)GG*DD*4);
  unsigned short* W1T    = (unsigned short*)alloc((size_t)LL*D2*DD*2);
  unsigned short* W2T    = (unsigned short*)alloc((size_t)LL*D2*DD*2);
  // zero region: stats_all [LL][8][256] | vbuf_all [5][GG*DD] | counts [NN]
  const int STATS_F = LL*8*256;          // 10240
  const int VBUF_F  = 5*GG*DD;           // 81920
  const int ZTOT    = STATS_F + VBUF_F + NN;
  float* zeroreg = (float*)alloc((size_t)ZTOT*4);
  float* stats_all = zeroreg;
  float* vbuf_all  = zeroreg + STATS_F;
  int*   counts    = (int*)(zeroreg + STATS_F + VBUF_F);
  int*   startp = (int*)  alloc((size_t)(NN+1)*4);
  int*   cursor = (int*)  alloc((size_t)NN*4);
  int*   bsums  = (int*)  alloc(128*4);
  int*   csr_src= (int*)  alloc((size_t)CSRP_MAX*4);
  unsigned short* csr_eah = (unsigned short*)alloc((size_t)CSRP_MAX*8*2);

  const int nb_scan = (NN + SCAN_B - 1)/SCAN_B;   // 98
  const int row_blocks = (NN + 127)/128;           // 391
  const int hap_blocks = (NN + HROWS - 1)/HROWS;   // 1563
  const int ew_blocks = (NN*32 + 255)/256;         // 6250

  // ---- setup ----
  zero_kernel<<<(ZTOT + 255)/256, 256, 0, stream>>>(zeroreg, ZTOT);
  csrinit_kernel<<<(CSRP_MAX + 255)/256, 256, 0, stream>>>(csr_src, csr_eah);
  count_kernel<<<EE/256, 256, 0, stream>>>(ei, counts);
  scan1_kernel<<<nb_scan, SCAN_B, 0, stream>>>(counts, bsums, NN);
  scan2_kernel<<<1, 64, 0, stream>>>(bsums, nb_scan);
  scan3_kernel<<<nb_scan, SCAN_B, 0, stream>>>(counts, bsums, startp, cursor, NN);
  fillcvt_kernel<<<EE/256, 256, 0, stream>>>(ei, edge_attr, cursor, csr_src, csr_eah);
  wtrans_kernel<<<(2*LL*DD*D2 + 255)/256, 256, 0, stream>>>(W1, W2, W1T, W2T);
  init_kernel<<<row_blocks, 128, 0, stream>>>(x, batch, node_emb, vn_emb, hin_bf, vbuf_all, vn);

  for (int l = 0; l < LL; ++l){
    float* st    = stats_all + (size_t)l*8*256;
    float* sum1  = st + 0*256, *sq1  = st + 1*256;
    float* sum2  = st + 2*256, *sq2  = st + 3*256;
    float* sumv1 = st + 4*256, *sqv1 = st + 5*256;
    float* sumv2 = st + 6*256, *sqv2 = st + 7*256;

    agg4_kernel<<<NN/4, 256, 0, stream>>>(hin_bf, csr_src, csr_eah, startp,
                                          edge_W + (size_t)l*7*DD, edge_b + (size_t)l*DD, eps, l, zy);
    gemm1_kernel<<<dim3(row_blocks, 2), 256, 0, stream>>>(zy, W1T + (size_t)l*32768,
                                                          b1 + (size_t)l*D2, y1h, sum1, sq1);
    if (l != LL-1){
      gemm2_kernel<0><<<row_blocks, 256, 0, stream>>>(y1h, sum1, sq1,
                                                      bn1_g + (size_t)l*D2, bn1_b + (size_t)l*D2,
                                                      W2T + (size_t)l*32768, b2 + (size_t)l*DD,
                                                      zy, nullptr, sum2, sq2);
      float* vbufl = vbuf_all + (size_t)l*GG*DD;
      float* vbufn = vbuf_all + (size_t)(l+1)*GG*DD;
      vmlp1_kernel<<<GG, 256, 0, stream>>>(vn, vbufl, vn_W1 + (size_t)l*DD*D2, vn_b1 + (size_t)l*D2,
                                           yv1, sumv1, sqv1);
      vmlp2_kernel<<<GG, 128, 0, stream>>>(yv1, sumv1, sqv1,
                                           vn_bn1_g + (size_t)l*D2, vn_bn1_b + (size_t)l*D2,
                                           vn_W2 + (size_t)l*D2*DD, vn_b2 + (size_t)l*DD,
                                           yv2, sumv2, sqv2);
      va_kernel<<<(GG*DD + 255)/256, 256, 0, stream>>>(yv2, sumv2, sqv2,
                                                       vn_bn2_g + (size_t)l*DD, vn_bn2_b + (size_t)l*DD, vn);
      happly_fused_kernel<<<hap_blocks, 128, 0, stream>>>(zy, sum2, sq2,
                                                          bn_g + (size_t)l*DD, bn_b + (size_t)l*DD,
                                                          vn, batch, hin_bf, vbufn);
    } else {
      gemm2_kernel<1><<<row_blocks, 256, 0, stream>>>(y1h, sum1, sq1,
                                                      bn1_g + (size_t)l*D2, bn1_b + (size_t)l*D2,
                                                      W2T + (size_t)l*32768, b2 + (size_t)l*DD,
                                                      nullptr, hout, sum2, sq2);
      happly_final_kernel<<<ew_blocks, 256, 0, stream>>>(hout, sum2, sq2,
                                                         bn_g + (size_t)l*DD, bn_b + (size_t)l*DD);
    }
  }
  (void)in_sizes; (void)n_in; (void)out_size; (void)ws_size;
}